// Round 12
// baseline (158.746 us; speedup 1.0000x reference)
//
#include <hip/hip_runtime.h>
#include <hip/hip_bf16.h>

typedef __attribute__((ext_vector_type(8))) short short8;
typedef __attribute__((ext_vector_type(4))) int intx4;
typedef __attribute__((ext_vector_type(2))) float floatx2;
typedef __attribute__((ext_vector_type(4))) float f32x4;

#define CH 64

__device__ __forceinline__ ushort f2b(float f) {
  __hip_bfloat16 h = __float2bfloat16(f);
  return *reinterpret_cast<ushort*>(&h);
}
__device__ __forceinline__ float b2f(ushort u) {
  return __uint_as_float(((unsigned)u) << 16);
}
// HW fp8 e4m3 encode: 1 inst/value
__device__ __forceinline__ unsigned char f2e4(float f) {
  int p = __builtin_amdgcn_cvt_pk_fp8_f32(f, f, 0, false);
  return (unsigned char)(p & 0xff);
}
__device__ __forceinline__ void wave_lds_sync() {
  asm volatile("s_waitcnt lgkmcnt(0)" ::: "memory");
  __builtin_amdgcn_wave_barrier();
}
// async global->LDS, 16B per lane, linear dest (wave-uniform base + lane*16)
__device__ __forceinline__ void gload_lds16(const void* g, void* l) {
  __builtin_amdgcn_global_load_lds(
      (const __attribute__((address_space(1))) void*)g,
      (__attribute__((address_space(3))) void*)l, 16, 0, 0);
}

// ------ pre: convert X->bf16, convert+transpose W, histogram ---------------
// blocks [0,nxb): X cvt; [nxb,nxb+256): W cvt; rest: hist (counts memset'd)
__global__ __launch_bounds__(256) void pre_kernel(
    const float* __restrict__ X, ushort* __restrict__ Xb, int nX,
    const float* __restrict__ Wq, const float* __restrict__ Wk,
    const float* __restrict__ Wv, const float* __restrict__ Wo,
    ushort* __restrict__ Wt, const int* __restrict__ src,
    int* __restrict__ counts, int E, int nxb) {
  __shared__ float L[32][33];
  int b = blockIdx.x;
  int t = threadIdx.x;
  if (b < nxb) {
    int i = (b * 256 + t) * 8;
    if (i >= nX) return;
    float4 x0 = *reinterpret_cast<const float4*>(X + i);
    float4 x1 = *reinterpret_cast<const float4*>(X + i + 4);
    short8 o;
    o[0] = (short)f2b(x0.x); o[1] = (short)f2b(x0.y);
    o[2] = (short)f2b(x0.z); o[3] = (short)f2b(x0.w);
    o[4] = (short)f2b(x1.x); o[5] = (short)f2b(x1.y);
    o[6] = (short)f2b(x1.z); o[7] = (short)f2b(x1.w);
    *reinterpret_cast<short8*>(Xb + i) = o;
  } else if (b < nxb + 256) {
    int bx = b - nxb;
    int mat = bx >> 6;
    int tile = bx & 63;
    int tr = (tile >> 3) * 32;
    int tc = (tile & 7) * 32;
    const float* W = (mat == 0) ? Wq : (mat == 1) ? Wk : (mat == 2) ? Wv : Wo;
    int c = t & 31, r8 = t >> 5;
#pragma unroll
    for (int rr = 0; rr < 4; ++rr) {
      int r = r8 + rr * 8;
      L[r][c] = W[(size_t)(tr + r) * 256 + tc + c];
    }
    __syncthreads();
#pragma unroll
    for (int rr = 0; rr < 4; ++rr) {
      int cc = r8 + rr * 8;
      Wt[(size_t)(mat * 256 + tc + cc) * 256 + tr + c] = f2b(L[c][cc]);
    }
  } else {
    int e = (b - nxb - 256) * 256 + t;
    if (e < E) atomicAdd(&counts[src[e]], 1);
  }
}

// ------ QKV MFMA GEMM: global_load_lds staging, swizzled-source, XCD-chunked
// LDS layout per tile: [128 rows][64 bf16] in 1KB groups of 8 rows; content
// chunk kc of row r sits at chunk position kc ^ (r&7)  (16B chunks).
// global_load_lds writes linear lane*16 -> source lane l loads row 8g+(l>>3),
// col-chunk (l&7)^(l>>3) (involution), reproducing the swizzled layout.
__global__ __launch_bounds__(256) void qkv_gemm(
    const ushort* __restrict__ Xb, const ushort* __restrict__ Wt,
    ushort* __restrict__ Qb, unsigned char* __restrict__ Kb8,
    unsigned char* __restrict__ Vb8, int N, int ngemm) {
  __shared__ ushort sA[128 * 64];
  __shared__ ushort sB[128 * 64];
  int bid = blockIdx.x;
  int t = threadIdx.x;
  // XCD-bijective swizzle (m204): panel-sharing blocks -> one XCD
  int q = ngemm >> 3, r = ngemm & 7;
  int xcd = bid & 7;
  int wgid = (xcd < r ? xcd * (q + 1) : r * (q + 1) + (xcd - r) * q) + (bid >> 3);
  int bx = wgid / 6, by = wgid % 6;
  char* cA = (char*)sA;
  char* cB = (char*)sB;
  int lane = t & 63, w = t >> 6;
  int wr = w >> 1, wc = w & 1;
  int row0 = bx * 128;
  int lr = lane & 15, kg = lane >> 4;

  // source mapping for this lane within each 8-row group
  int srow = lane >> 3;                 // row within group (0..7)
  int skc = (lane & 7) ^ srow;          // swizzled source col-chunk (0..7)
  // wave w stages groups 4w..4w+3 for A and for B
  int garow[4], gbrow[4];
#pragma unroll
  for (int gi = 0; gi < 4; ++gi) {
    int grp = w * 4 + gi;
    garow[gi] = min(row0 + grp * 8 + srow, N - 1);
    gbrow[gi] = by * 128 + grp * 8 + srow;
  }

  f32x4 acc[4][4] = {};
  for (int k0 = 0; k0 < 256; k0 += 64) {
#pragma unroll
    for (int gi = 0; gi < 4; ++gi) {
      int grp = w * 4 + gi;
      gload_lds16(Xb + (size_t)garow[gi] * 256 + k0 + skc * 8, cA + grp * 1024);
      gload_lds16(Wt + (size_t)gbrow[gi] * 256 + k0 + skc * 8, cB + grp * 1024);
    }
    asm volatile("s_waitcnt vmcnt(0)" ::: "memory");
    __syncthreads();
#pragma unroll
    for (int ks = 0; ks < 2; ++ks) {
      short8 af[4], bf[4];
#pragma unroll
      for (int fr = 0; fr < 4; ++fr) {
        int row = wr * 64 + fr * 16 + lr;
        af[fr] = *reinterpret_cast<const short8*>(
            cA + ((row * 128 + ks * 64 + kg * 16) ^ ((row & 7) << 4)));
      }
#pragma unroll
      for (int fc = 0; fc < 4; ++fc) {
        int col = wc * 64 + fc * 16 + lr;
        bf[fc] = *reinterpret_cast<const short8*>(
            cB + ((col * 128 + ks * 64 + kg * 16) ^ ((col & 7) << 4)));
      }
#pragma unroll
      for (int fr = 0; fr < 4; ++fr)
#pragma unroll
        for (int fc = 0; fc < 4; ++fc)
          acc[fr][fc] = __builtin_amdgcn_mfma_f32_16x16x32_bf16(af[fr], bf[fc], acc[fr][fc], 0, 0, 0);
    }
    __syncthreads();
  }
  int orow = kg * 4;
  int mat = by >> 1;  // 0=Q, 1=K, 2=V
#pragma unroll
  for (int fr = 0; fr < 4; ++fr)
#pragma unroll
    for (int fc = 0; fc < 4; ++fc)
#pragma unroll
      for (int r2 = 0; r2 < 4; ++r2) {
        int row = row0 + wr * 64 + fr * 16 + orow + r2;
        int col = (by & 1) * 128 + wc * 64 + fc * 16 + lr;
        if (row < N) {
          float v = acc[fr][fc][r2];
          if (mat == 0)      Qb[(size_t)row * 256 + col]  = f2b(v);
          else if (mat == 1) Kb8[(size_t)row * 256 + col] = f2e4(v);
          else               Vb8[(size_t)row * 256 + col] = f2e4(v);
        }
      }
}

// ---------------- scan: single block, 1024 threads ----------------
__global__ __launch_bounds__(1024) void scan_kernel(
    const int* __restrict__ counts, int* __restrict__ offs, int* __restrict__ cursor, int N) {
  __shared__ int wsum[16];
  __shared__ int wexc[16];
  __shared__ int s_total;
  int t = threadIdx.x;
  int lane = t & 63, wv = t >> 6;
  int per = (N + 1023) >> 10;
  int b0 = t * per;
  int e0 = min(b0 + per, N);
  int sum = 0;
  for (int i = b0; i < e0; ++i) sum += counts[i];
  int x = sum;
#pragma unroll
  for (int off = 1; off < 64; off <<= 1) {
    int y = __shfl_up(x, off);
    if (lane >= off) x += y;
  }
  if (lane == 63) wsum[wv] = x;
  __syncthreads();
  if (t < 64) {
    int s = (lane < 16) ? wsum[lane] : 0;
    int xs = s;
#pragma unroll
    for (int off = 1; off < 16; off <<= 1) {
      int y = __shfl_up(xs, off);
      if (lane >= off) xs += y;
    }
    if (lane < 16) wexc[lane] = xs - s;
    if (lane == 15) s_total = xs;
  }
  __syncthreads();
  int running = wexc[wv] + (x - sum);
  for (int i = b0; i < e0; ++i) {
    int c = counts[i];
    offs[i] = running;
    cursor[i] = running;
    running += c;
  }
  if (t == 0) offs[N] = s_total;
}

// ---------------- scatter: packed int2{tgt, w_bits} ----------------
__global__ void scatter_kernel(const int* __restrict__ src, const int* __restrict__ tgt,
                               const float* __restrict__ ew, int* __restrict__ cursor,
                               int2* __restrict__ ews, int E) {
  int e = blockIdx.x * blockDim.x + threadIdx.x;
  if (e < E) {
    int pos = atomicAdd(&cursor[src[e]], 1);
    ews[pos] = make_int2(tgt[e], __float_as_int(ew[e]));
  }
}

// -------- per-node attention: one WAVE per node; fp8 K/V + HW cvt -----------
__global__ __launch_bounds__(256) void attn_kernel(
    const ushort* __restrict__ Qb, const unsigned char* __restrict__ Kb8,
    const unsigned char* __restrict__ Vb8,
    const int* __restrict__ offs, const int2* __restrict__ ews,
    const float* __restrict__ We, ushort* __restrict__ AGGb, int N) {
  __shared__ float s_p[4][CH][8];
  __shared__ int s_tgt[4][CH];
  __shared__ float s_w[4][CH];
  int t = threadIdx.x;
  int w = t >> 6;
  int l = t & 63;
  int i = blockIdx.x * 4 + w;
  if (i >= N) return;
  int e8 = l >> 3;
  int h = l & 7;
  int hacc = l >> 3;
  const float scale = 0.17677669529663687f;
  float we = We[h];

  float qf[32];
  {
    const short8* qr = reinterpret_cast<const short8*>(Qb + (size_t)i * 256 + h * 32);
#pragma unroll
    for (int d = 0; d < 4; ++d) {
      short8 qv = qr[d];
#pragma unroll
      for (int x = 0; x < 8; ++x) qf[d * 8 + x] = b2f((ushort)qv[x]);
    }
  }

  float m = -1e30f, lsum = 0.f;
  float acc0 = 0.f, acc1 = 0.f, acc2 = 0.f, acc3 = 0.f;
  int beg = offs[i], end = offs[i + 1];

  for (int base = beg; base < end; base += CH) {
    int cnt = min(CH, end - base);
    int cnt_pad = (cnt + 7) & ~7;  // >= 8 always
    {
      bool valid = l < cnt;
      int2 te = valid ? ews[base + l] : make_int2(i, 0);
      s_tgt[w][l] = te.x;
      s_w[w][l] = valid ? __int_as_float(te.y) : 0.f;
    }
    wave_lds_sync();

    // ---- score phase: depth-2 pipelined sections of 8 edges, fp8 K ----
    float s_local[8];
#pragma unroll
    for (int it = 0; it < 8; ++it) s_local[it] = -1e30f;

    intx4 kc[2], kn[2];
    {
      const intx4* p = reinterpret_cast<const intx4*>(
          Kb8 + (size_t)s_tgt[w][e8] * 256 + h * 32);
      kc[0] = p[0]; kc[1] = p[1];
    }
    if (8 < cnt_pad) {
      const intx4* p = reinterpret_cast<const intx4*>(
          Kb8 + (size_t)s_tgt[w][8 + e8] * 256 + h * 32);
      kn[0] = p[0]; kn[1] = p[1];
    }
    float cmax = -1e30f;
#pragma unroll
    for (int it = 0; it < 8; ++it) {
      if (it * 8 >= cnt_pad) break;  // wave-uniform
      float dot = 0.f;
#pragma unroll
      for (int c = 0; c < 2; ++c)
#pragma unroll
        for (int e = 0; e < 4; ++e) {
          floatx2 lo = __builtin_amdgcn_cvt_pk_f32_fp8(kc[c][e], false);
          floatx2 hi = __builtin_amdgcn_cvt_pk_f32_fp8(kc[c][e], true);
          int b0 = c * 16 + e * 4;
          dot += qf[b0] * lo[0] + qf[b0 + 1] * lo[1] + qf[b0 + 2] * hi[0] + qf[b0 + 3] * hi[1];
        }
      int j = it * 8 + e8;
      float s = (j < cnt) ? dot * scale + s_w[w][j] * we : -1e30f;
      s_local[it] = s;
      cmax = fmaxf(cmax, s);
      kc[0] = kn[0]; kc[1] = kn[1];
      if ((it + 2) * 8 < cnt_pad) {
        const intx4* p = reinterpret_cast<const intx4*>(
            Kb8 + (size_t)s_tgt[w][(it + 2) * 8 + e8] * 256 + h * 32);
        kn[0] = p[0]; kn[1] = p[1];
      }
    }
    cmax = fmaxf(cmax, __shfl_xor(cmax, 8));
    cmax = fmaxf(cmax, __shfl_xor(cmax, 16));
    cmax = fmaxf(cmax, __shfl_xor(cmax, 32));
    float newm = fmaxf(m, cmax);
    float f = __expf(m - newm);
    float psum = 0.f;
#pragma unroll
    for (int it = 0; it < 8; ++it) {
      if (it * 8 >= cnt_pad) break;
      int j = it * 8 + e8;
      float p = __expf(s_local[it] - newm);
      s_p[w][j][h] = p;
      psum += p;
    }
    psum += __shfl_xor(psum, 8);
    psum += __shfl_xor(psum, 16);
    psum += __shfl_xor(psum, 32);
    lsum = lsum * f + psum;
    m = newm;
    float f_acc = __shfl(f, hacc);
    acc0 *= f_acc; acc1 *= f_acc; acc2 *= f_acc; acc3 *= f_acc;
    wave_lds_sync();

    // ---- PV phase: 8-edge load batches, fp8 V (4B/lane), HW decode ----
#pragma unroll
    for (int g = 0; g < 8; ++g) {
      if (g * 8 >= cnt_pad) break;
      float pv[8];
      int vv[8];
#pragma unroll
      for (int k = 0; k < 8; ++k) {
        int j = g * 8 + k;
        pv[k] = s_p[w][j][hacc];
        vv[k] = *reinterpret_cast<const int*>(
            Vb8 + (size_t)s_tgt[w][j] * 256 + l * 4);
      }
#pragma unroll
      for (int k = 0; k < 8; ++k) {
        floatx2 lo = __builtin_amdgcn_cvt_pk_f32_fp8(vv[k], false);
        floatx2 hi = __builtin_amdgcn_cvt_pk_f32_fp8(vv[k], true);
        acc0 += pv[k] * lo[0];
        acc1 += pv[k] * lo[1];
        acc2 += pv[k] * hi[0];
        acc3 += pv[k] * hi[1];
      }
    }
    wave_lds_sync();
  }
  float lsum_acc = __shfl(lsum, hacc);
  float rinv = (lsum_acc > 0.f) ? 1.f / lsum_acc : 0.f;
  ushort4 o = make_ushort4(f2b(acc0 * rinv), f2b(acc1 * rinv),
                           f2b(acc2 * rinv), f2b(acc3 * rinv));
  *reinterpret_cast<ushort4*>(AGGb + (size_t)i * 256 + l * 4) = o;
}

// ------- output GEMM (LDS-staged, BM=64 BN=256) + residual + LayerNorm ------
__global__ __launch_bounds__(256) void out_ln(
    const ushort* __restrict__ AGGb, const ushort* __restrict__ Wot,
    const float* __restrict__ X, const float* __restrict__ g, const float* __restrict__ bb,
    float* __restrict__ out, int N) {
  __shared__ ushort sA[64 * 64];
  __shared__ ushort sB[256 * 64];
  char* cA = (char*)sA;
  char* cB = (char*)sB;
  int t = threadIdx.x;
  int lane = t & 63, w = t >> 6;
  int row0 = blockIdx.x * 64;
  int lr = lane & 15, kg = lane >> 4;
  f32x4 acc[16] = {};
  for (int k0 = 0; k0 < 256; k0 += 64) {
#pragma unroll
    for (int it = 0; it < 2; ++it) {
      int slot = t + it * 256;
      int row = slot >> 3, kc = slot & 7;
      int grow = min(row0 + row, N - 1);
      short8 va = *reinterpret_cast<const short8*>(AGGb + (size_t)grow * 256 + k0 + kc * 8);
      *reinterpret_cast<short8*>(cA + ((row * 128 + kc * 16) ^ ((row & 7) << 4))) = va;
    }
#pragma unroll
    for (int it = 0; it < 8; ++it) {
      int slot = t + it * 256;
      int col = slot >> 3, kc = slot & 7;
      short8 vb = *reinterpret_cast<const short8*>(Wot + (size_t)col * 256 + k0 + kc * 8);
      *reinterpret_cast<short8*>(cB + ((col * 128 + kc * 16) ^ ((col & 7) << 4))) = vb;
    }
    __syncthreads();
#pragma unroll
    for (int ks = 0; ks < 2; ++ks) {
      int arow = w * 16 + lr;
      short8 a = *reinterpret_cast<const short8*>(
          cA + ((arow * 128 + ks * 64 + kg * 16) ^ ((arow & 7) << 4)));
#pragma unroll
      for (int fc = 0; fc < 16; ++fc) {
        int col = fc * 16 + lr;
        short8 b = *reinterpret_cast<const short8*>(
            cB + ((col * 128 + ks * 64 + kg * 16) ^ ((col & 7) << 4)));
        acc[fc] = __builtin_amdgcn_mfma_f32_16x16x32_bf16(a, b, acc[fc], 0, 0, 0);
      }
    }
    __syncthreads();
  }
  float g16[16], b16[16];
#pragma unroll
  for (int fc = 0; fc < 16; ++fc) {
    g16[fc] = g[fc * 16 + lr];
    b16[fc] = bb[fc * 16 + lr];
  }
#pragma unroll
  for (int r = 0; r < 4; ++r) {
    int rowl = kg * 4 + r;
    int grow = row0 + w * 16 + rowl;
    int growc = min(grow, N - 1);
    float xv[16];
    float s = 0.f, ss = 0.f;
#pragma unroll
    for (int fc = 0; fc < 16; ++fc) {
      float v = acc[fc][r] + X[(size_t)growc * 256 + fc * 16 + lr];
      xv[fc] = v;
      s += v;
      ss += v * v;
    }
    s += __shfl_xor(s, 1);  ss += __shfl_xor(ss, 1);
    s += __shfl_xor(s, 2);  ss += __shfl_xor(ss, 2);
    s += __shfl_xor(s, 4);  ss += __shfl_xor(ss, 4);
    s += __shfl_xor(s, 8);  ss += __shfl_xor(ss, 8);
    float mu = s * (1.f / 256.f);
    float var = ss * (1.f / 256.f) - mu * mu;
    float rs = rsqrtf(var + 1e-5f);
    if (grow < N) {
#pragma unroll
      for (int fc = 0; fc < 16; ++fc)
        out[(size_t)grow * 256 + fc * 16 + lr] = (xv[fc] - mu) * rs * g16[fc] + b16[fc];
    }
  }
}

extern "C" void kernel_launch(void* const* d_in, const int* in_sizes, int n_in,
                              void* d_out, int out_size, void* d_ws, size_t ws_size,
                              hipStream_t stream) {
  const float* X  = (const float*)d_in[0];
  const int* eidx = (const int*)d_in[1];
  const float* ew = (const float*)d_in[2];
  const float* Wq = (const float*)d_in[3];
  const float* Wk = (const float*)d_in[4];
  const float* Wv = (const float*)d_in[5];
  const float* We = (const float*)d_in[6];
  const float* Wo = (const float*)d_in[7];
  const float* g  = (const float*)d_in[8];
  const float* b  = (const float*)d_in[9];
  int N = in_sizes[0] / 256;
  int E = in_sizes[1] / 2;
  const int* src = eidx;
  const int* tgt = eidx + E;
  float* out = (float*)d_out;

  char* w = (char*)d_ws;
  ushort* Xb   = (ushort*)w;        w += (size_t)N * 256 * 2;
  ushort* Wt   = (ushort*)w;        w += (size_t)1024 * 256 * 2;
  ushort* Qb   = (ushort*)w;        w += (size_t)N * 256 * 2;
  unsigned char* Kb8 = (unsigned char*)w;  w += (size_t)N * 256;
  unsigned char* Vb8 = (unsigned char*)w;  w += (size_t)N * 256;
  ushort* AGGb = (ushort*)w;        w += (size_t)N * 256 * 2;
  int* counts  = (int*)w;           w += (size_t)N * 4;
  int* offs    = (int*)w;           w += (size_t)(N + 1) * 4;
  int* cursor  = (int*)w;           w += (size_t)N * 4;
  int2* ews    = (int2*)w;          w += (size_t)E * 8;
  const ushort* Wot = Wt + (size_t)768 * 256;

  hipMemsetAsync(counts, 0, (size_t)N * 4, stream);

  int nX = N * 256;
  int nxb = (nX / 8 + 255) / 256;
  int nhist = (E + 255) / 256;
  pre_kernel<<<nxb + 256 + nhist, 256, 0, stream>>>(X, Xb, nX, Wq, Wk, Wv, Wo, Wt, src, counts, E, nxb);

  int ngemm = ((N + 127) / 128) * 6;
  qkv_gemm<<<ngemm, 256, 0, stream>>>(Xb, Wt, Qb, Kb8, Vb8, N, ngemm);

  scan_kernel<<<1, 1024, 0, stream>>>(counts, offs, cursor, N);
  scatter_kernel<<<(E + 255) / 256, 256, 0, stream>>>(src, tgt, ew, cursor, ews, E);
  attn_kernel<<<(N + 3) / 4, 256, 0, stream>>>(Qb, Kb8, Vb8, offs, ews, We, AGGb, N);
  out_ln<<<(N + 63) / 64, 256, 0, stream>>>(AGGb, Wot, X, g, b, out, N);
}

// Round 13
// 146.050 us; speedup vs baseline: 1.0869x; 1.0869x over previous
//
#include <hip/hip_runtime.h>
#include <hip/hip_bf16.h>

typedef __attribute__((ext_vector_type(8))) short short8;
typedef __attribute__((ext_vector_type(4))) int intx4;
typedef __attribute__((ext_vector_type(2))) float floatx2;
typedef __attribute__((ext_vector_type(4))) float f32x4;

#define CH 64

__device__ __forceinline__ ushort f2b(float f) {
  __hip_bfloat16 h = __float2bfloat16(f);
  return *reinterpret_cast<ushort*>(&h);
}
__device__ __forceinline__ float b2f(ushort u) {
  return __uint_as_float(((unsigned)u) << 16);
}
// HW fp8 e4m3 encode: 1 inst/value
__device__ __forceinline__ unsigned char f2e4(float f) {
  int p = __builtin_amdgcn_cvt_pk_fp8_f32(f, f, 0, false);
  return (unsigned char)(p & 0xff);
}
__device__ __forceinline__ void wave_lds_sync() {
  asm volatile("s_waitcnt lgkmcnt(0)" ::: "memory");
  __builtin_amdgcn_wave_barrier();
}
// async global->LDS, 16B per lane, linear dest (wave-uniform base + lane*16)
__device__ __forceinline__ void gload_lds16(const void* g, void* l) {
  __builtin_amdgcn_global_load_lds(
      (const __attribute__((address_space(1))) void*)g,
      (__attribute__((address_space(3))) void*)l, 16, 0, 0);
}

// ------ pre: convert X->bf16, convert+transpose W, zero counts --------------
__global__ __launch_bounds__(256) void pre_kernel(
    const float* __restrict__ X, ushort* __restrict__ Xb, int nX,
    const float* __restrict__ Wq, const float* __restrict__ Wk,
    const float* __restrict__ Wv, const float* __restrict__ Wo,
    ushort* __restrict__ Wt, int* __restrict__ counts, int N, int nxb) {
  __shared__ float L[32][33];
  int b = blockIdx.x;
  int t = threadIdx.x;
  if (b < nxb) {
    int i = (b * 256 + t) * 8;
    if (i >= nX) return;
    float4 x0 = *reinterpret_cast<const float4*>(X + i);
    float4 x1 = *reinterpret_cast<const float4*>(X + i + 4);
    short8 o;
    o[0] = (short)f2b(x0.x); o[1] = (short)f2b(x0.y);
    o[2] = (short)f2b(x0.z); o[3] = (short)f2b(x0.w);
    o[4] = (short)f2b(x1.x); o[5] = (short)f2b(x1.y);
    o[6] = (short)f2b(x1.z); o[7] = (short)f2b(x1.w);
    *reinterpret_cast<short8*>(Xb + i) = o;
  } else if (b < nxb + 256) {
    int bx = b - nxb;
    int mat = bx >> 6;
    int tile = bx & 63;
    int tr = (tile >> 3) * 32;
    int tc = (tile & 7) * 32;
    const float* W = (mat == 0) ? Wq : (mat == 1) ? Wk : (mat == 2) ? Wv : Wo;
    int c = t & 31, r8 = t >> 5;
#pragma unroll
    for (int rr = 0; rr < 4; ++rr) {
      int r = r8 + rr * 8;
      L[r][c] = W[(size_t)(tr + r) * 256 + tc + c];
    }
    __syncthreads();
#pragma unroll
    for (int rr = 0; rr < 4; ++rr) {
      int cc = r8 + rr * 8;
      Wt[(size_t)(mat * 256 + tc + cc) * 256 + tr + c] = f2b(L[c][cc]);
    }
  } else {
    int i = (b - nxb - 256) * 256 + t;
    if (i < N) counts[i] = 0;
  }
}

// ------ QKV MFMA GEMM: global_load_lds, double-buffered, XCD-chunked + hist -
// LDS per buffer: [128 rows][64 bf16], 1KB per 8-row group; content chunk kc
// of row r at position kc ^ (r&7). Linear LDS dest + inverse-swizzled source.
__global__ __launch_bounds__(256) void qkv_gemm(
    const ushort* __restrict__ Xb, const ushort* __restrict__ Wt,
    ushort* __restrict__ Qb, unsigned char* __restrict__ Kb8,
    unsigned char* __restrict__ Vb8, const int* __restrict__ src,
    int* __restrict__ counts, int N, int E, int ngemm) {
  __shared__ ushort sA[2][8192];
  __shared__ ushort sB[2][8192];
  int bid = blockIdx.x;
  int t = threadIdx.x;
  if (bid >= ngemm) {
    int e = (bid - ngemm) * 256 + t;
    if (e < E) atomicAdd(&counts[src[e]], 1);
    return;
  }
  // XCD-bijective swizzle (m204): panel-sharing blocks -> one XCD
  int q = ngemm >> 3, r = ngemm & 7;
  int xcd = bid & 7;
  int wgid = (xcd < r ? xcd * (q + 1) : r * (q + 1) + (xcd - r) * q) + (bid >> 3);
  int bx = wgid / 6, by = wgid % 6;
  int lane = t & 63, w = t >> 6;
  int wr = w >> 1, wc = w & 1;
  int row0 = bx * 128;
  int lr = lane & 15, kg = lane >> 4;

  int srow = lane >> 3;         // row within 8-row group
  int skc = (lane & 7) ^ srow;  // swizzled source col-chunk (involution)
  int garow[4], gbrow[4];
#pragma unroll
  for (int gi = 0; gi < 4; ++gi) {
    int grp = w * 4 + gi;
    garow[gi] = min(row0 + grp * 8 + srow, N - 1);
    gbrow[gi] = by * 128 + grp * 8 + srow;
  }

#define STAGE(BA, BB, K0)                                                       \
  {                                                                             \
    _Pragma("unroll") for (int gi = 0; gi < 4; ++gi) {                          \
      int grp = w * 4 + gi;                                                     \
      gload_lds16(Xb + (size_t)garow[gi] * 256 + (K0) + skc * 8,                \
                  (char*)(BA) + grp * 1024);                                    \
      gload_lds16(Wt + (size_t)gbrow[gi] * 256 + (K0) + skc * 8,                \
                  (char*)(BB) + grp * 1024);                                    \
    }                                                                           \
  }

  f32x4 acc[4][4] = {};
  STAGE(sA[0], sB[0], 0);
  asm volatile("s_waitcnt vmcnt(0)" ::: "memory");
  __syncthreads();
#pragma unroll
  for (int k = 0; k < 4; ++k) {
    int cur = k & 1;
    if (k < 3) STAGE(sA[cur ^ 1], sB[cur ^ 1], (k + 1) * 64);  // issue-early
    char* cA = (char*)sA[cur];
    char* cB = (char*)sB[cur];
#pragma unroll
    for (int ks = 0; ks < 2; ++ks) {
      short8 af[4], bf[4];
#pragma unroll
      for (int fr = 0; fr < 4; ++fr) {
        int row = wr * 64 + fr * 16 + lr;
        af[fr] = *reinterpret_cast<const short8*>(
            cA + ((row * 128 + ks * 64 + kg * 16) ^ ((row & 7) << 4)));
      }
#pragma unroll
      for (int fc = 0; fc < 4; ++fc) {
        int col = wc * 64 + fc * 16 + lr;
        bf[fc] = *reinterpret_cast<const short8*>(
            cB + ((col * 128 + ks * 64 + kg * 16) ^ ((col & 7) << 4)));
      }
#pragma unroll
      for (int fr = 0; fr < 4; ++fr)
#pragma unroll
        for (int fc = 0; fc < 4; ++fc)
          acc[fr][fc] = __builtin_amdgcn_mfma_f32_16x16x32_bf16(af[fr], bf[fc], acc[fr][fc], 0, 0, 0);
    }
    asm volatile("s_waitcnt vmcnt(0)" ::: "memory");  // next-buffer loads done
    __syncthreads();                                  // all waves done with cur
  }
#undef STAGE
  int orow = kg * 4;
  int mat = by >> 1;  // 0=Q, 1=K, 2=V
#pragma unroll
  for (int fr = 0; fr < 4; ++fr)
#pragma unroll
    for (int fc = 0; fc < 4; ++fc)
#pragma unroll
      for (int r2 = 0; r2 < 4; ++r2) {
        int row = row0 + wr * 64 + fr * 16 + orow + r2;
        int col = (by & 1) * 128 + wc * 64 + fc * 16 + lr;
        if (row < N) {
          float v = acc[fr][fc][r2];
          if (mat == 0)      Qb[(size_t)row * 256 + col]  = f2b(v);
          else if (mat == 1) Kb8[(size_t)row * 256 + col] = f2e4(v);
          else               Vb8[(size_t)row * 256 + col] = f2e4(v);
        }
      }
}

// ---------------- scan: single block, 1024 threads ----------------
__global__ __launch_bounds__(1024) void scan_kernel(
    const int* __restrict__ counts, int* __restrict__ offs, int* __restrict__ cursor, int N) {
  __shared__ int wsum[16];
  __shared__ int wexc[16];
  __shared__ int s_total;
  int t = threadIdx.x;
  int lane = t & 63, wv = t >> 6;
  int per = (N + 1023) >> 10;
  int b0 = t * per;
  int e0 = min(b0 + per, N);
  int sum = 0;
  for (int i = b0; i < e0; ++i) sum += counts[i];
  int x = sum;
#pragma unroll
  for (int off = 1; off < 64; off <<= 1) {
    int y = __shfl_up(x, off);
    if (lane >= off) x += y;
  }
  if (lane == 63) wsum[wv] = x;
  __syncthreads();
  if (t < 64) {
    int s = (lane < 16) ? wsum[lane] : 0;
    int xs = s;
#pragma unroll
    for (int off = 1; off < 16; off <<= 1) {
      int y = __shfl_up(xs, off);
      if (lane >= off) xs += y;
    }
    if (lane < 16) wexc[lane] = xs - s;
    if (lane == 15) s_total = xs;
  }
  __syncthreads();
  int running = wexc[wv] + (x - sum);
  for (int i = b0; i < e0; ++i) {
    int c = counts[i];
    offs[i] = running;
    cursor[i] = running;
    running += c;
  }
  if (t == 0) offs[N] = s_total;
}

// ---------------- scatter: packed int2{tgt, w_bits} ----------------
__global__ void scatter_kernel(const int* __restrict__ src, const int* __restrict__ tgt,
                               const float* __restrict__ ew, int* __restrict__ cursor,
                               int2* __restrict__ ews, int E) {
  int e = blockIdx.x * blockDim.x + threadIdx.x;
  if (e < E) {
    int pos = atomicAdd(&cursor[src[e]], 1);
    ews[pos] = make_int2(tgt[e], __float_as_int(ew[e]));
  }
}

// -------- per-node attention: one WAVE per node; fp8 K/V, packed f32 math ---
__global__ __launch_bounds__(256) void attn_kernel(
    const ushort* __restrict__ Qb, const unsigned char* __restrict__ Kb8,
    const unsigned char* __restrict__ Vb8,
    const int* __restrict__ offs, const int2* __restrict__ ews,
    const float* __restrict__ We, ushort* __restrict__ AGGb, int N) {
  __shared__ float s_p[4][CH][8];
  __shared__ int s_tgt[4][CH];
  __shared__ float s_w[4][CH];
  int t = threadIdx.x;
  int w = t >> 6;
  int l = t & 63;
  int i = blockIdx.x * 4 + w;
  if (i >= N) return;
  int e8 = l >> 3;
  int h = l & 7;
  int hacc = l >> 3;
  const float scale = 0.17677669529663687f;
  float we = We[h];

  // Q fragment as packed float2 (feeds v_pk_fma_f32)
  floatx2 qf2[16];
  {
    const short8* qr = reinterpret_cast<const short8*>(Qb + (size_t)i * 256 + h * 32);
#pragma unroll
    for (int d = 0; d < 4; ++d) {
      short8 qv = qr[d];
#pragma unroll
      for (int x = 0; x < 4; ++x) {
        floatx2 p;
        p[0] = b2f((ushort)qv[2 * x]);
        p[1] = b2f((ushort)qv[2 * x + 1]);
        qf2[d * 4 + x] = p;
      }
    }
  }

  float m = -1e30f, lsum = 0.f;
  floatx2 accA = {0.f, 0.f};  // dims l*4+0, l*4+1
  floatx2 accB = {0.f, 0.f};  // dims l*4+2, l*4+3
  int beg = offs[i], end = offs[i + 1];

  for (int base = beg; base < end; base += CH) {
    int cnt = min(CH, end - base);
    int cnt_pad = (cnt + 7) & ~7;  // >= 8 always
    {
      bool valid = l < cnt;
      int2 te = valid ? ews[base + l] : make_int2(i, 0);
      s_tgt[w][l] = te.x;
      s_w[w][l] = valid ? __int_as_float(te.y) : 0.f;
    }
    wave_lds_sync();

    // ---- score phase: depth-2 pipelined sections of 8 edges, fp8 K ----
    float s_local[8];
#pragma unroll
    for (int it = 0; it < 8; ++it) s_local[it] = -1e30f;

    intx4 kc[2], kn[2];
    {
      const intx4* p = reinterpret_cast<const intx4*>(
          Kb8 + (size_t)s_tgt[w][e8] * 256 + h * 32);
      kc[0] = p[0]; kc[1] = p[1];
    }
    if (8 < cnt_pad) {
      const intx4* p = reinterpret_cast<const intx4*>(
          Kb8 + (size_t)s_tgt[w][8 + e8] * 256 + h * 32);
      kn[0] = p[0]; kn[1] = p[1];
    }
    float cmax = -1e30f;
#pragma unroll
    for (int it = 0; it < 8; ++it) {
      if (it * 8 >= cnt_pad) break;  // wave-uniform
      floatx2 dot2 = {0.f, 0.f};
#pragma unroll
      for (int c = 0; c < 2; ++c)
#pragma unroll
        for (int e = 0; e < 4; ++e) {
          floatx2 lo = __builtin_amdgcn_cvt_pk_f32_fp8(kc[c][e], false);
          floatx2 hi = __builtin_amdgcn_cvt_pk_f32_fp8(kc[c][e], true);
          int b0 = c * 8 + e * 2;
          dot2 += qf2[b0] * lo;
          dot2 += qf2[b0 + 1] * hi;
        }
      float dot = dot2[0] + dot2[1];
      int j = it * 8 + e8;
      float s = (j < cnt) ? dot * scale + s_w[w][j] * we : -1e30f;
      s_local[it] = s;
      cmax = fmaxf(cmax, s);
      kc[0] = kn[0]; kc[1] = kn[1];
      if ((it + 2) * 8 < cnt_pad) {
        const intx4* p = reinterpret_cast<const intx4*>(
            Kb8 + (size_t)s_tgt[w][(it + 2) * 8 + e8] * 256 + h * 32);
        kn[0] = p[0]; kn[1] = p[1];
      }
    }
    cmax = fmaxf(cmax, __shfl_xor(cmax, 8));
    cmax = fmaxf(cmax, __shfl_xor(cmax, 16));
    cmax = fmaxf(cmax, __shfl_xor(cmax, 32));
    float newm = fmaxf(m, cmax);
    float f = __expf(m - newm);
    float psum = 0.f;
#pragma unroll
    for (int it = 0; it < 8; ++it) {
      if (it * 8 >= cnt_pad) break;
      int j = it * 8 + e8;
      float p = __expf(s_local[it] - newm);
      s_p[w][j][h] = p;
      psum += p;
    }
    psum += __shfl_xor(psum, 8);
    psum += __shfl_xor(psum, 16);
    psum += __shfl_xor(psum, 32);
    lsum = lsum * f + psum;
    m = newm;
    float f_acc = __shfl(f, hacc);
    floatx2 f2v = {f_acc, f_acc};
    accA *= f2v;
    accB *= f2v;
    wave_lds_sync();

    // ---- PV phase: 8-edge load batches, fp8 V, packed FMA ----
#pragma unroll
    for (int g = 0; g < 8; ++g) {
      if (g * 8 >= cnt_pad) break;
      float pv[8];
      int vv[8];
#pragma unroll
      for (int k = 0; k < 8; ++k) {
        int j = g * 8 + k;
        pv[k] = s_p[w][j][hacc];
        vv[k] = *reinterpret_cast<const int*>(
            Vb8 + (size_t)s_tgt[w][j] * 256 + l * 4);
      }
#pragma unroll
      for (int k = 0; k < 8; ++k) {
        floatx2 lo = __builtin_amdgcn_cvt_pk_f32_fp8(vv[k], false);
        floatx2 hi = __builtin_amdgcn_cvt_pk_f32_fp8(vv[k], true);
        floatx2 p2 = {pv[k], pv[k]};
        accA += p2 * lo;
        accB += p2 * hi;
      }
    }
    wave_lds_sync();
  }
  float lsum_acc = __shfl(lsum, hacc);
  float rinv = (lsum_acc > 0.f) ? 1.f / lsum_acc : 0.f;
  ushort4 o = make_ushort4(f2b(accA[0] * rinv), f2b(accA[1] * rinv),
                           f2b(accB[0] * rinv), f2b(accB[1] * rinv));
  *reinterpret_cast<ushort4*>(AGGb + (size_t)i * 256 + l * 4) = o;
}

// ------- output GEMM (LDS-staged, BM=64 BN=256) + residual + LayerNorm ------
__global__ __launch_bounds__(256) void out_ln(
    const ushort* __restrict__ AGGb, const ushort* __restrict__ Wot,
    const float* __restrict__ X, const float* __restrict__ g, const float* __restrict__ bb,
    float* __restrict__ out, int N) {
  __shared__ ushort sA[64 * 64];
  __shared__ ushort sB[256 * 64];
  char* cA = (char*)sA;
  char* cB = (char*)sB;
  int t = threadIdx.x;
  int lane = t & 63, w = t >> 6;
  int row0 = blockIdx.x * 64;
  int lr = lane & 15, kg = lane >> 4;
  f32x4 acc[16] = {};
  for (int k0 = 0; k0 < 256; k0 += 64) {
#pragma unroll
    for (int it = 0; it < 2; ++it) {
      int slot = t + it * 256;
      int row = slot >> 3, kc = slot & 7;
      int grow = min(row0 + row, N - 1);
      short8 va = *reinterpret_cast<const short8*>(AGGb + (size_t)grow * 256 + k0 + kc * 8);
      *reinterpret_cast<short8*>(cA + ((row * 128 + kc * 16) ^ ((row & 7) << 4))) = va;
    }
#pragma unroll
    for (int it = 0; it < 8; ++it) {
      int slot = t + it * 256;
      int col = slot >> 3, kc = slot & 7;
      short8 vb = *reinterpret_cast<const short8*>(Wot + (size_t)col * 256 + k0 + kc * 8);
      *reinterpret_cast<short8*>(cB + ((col * 128 + kc * 16) ^ ((col & 7) << 4))) = vb;
    }
    __syncthreads();
#pragma unroll
    for (int ks = 0; ks < 2; ++ks) {
      int arow = w * 16 + lr;
      short8 a = *reinterpret_cast<const short8*>(
          cA + ((arow * 128 + ks * 64 + kg * 16) ^ ((arow & 7) << 4)));
#pragma unroll
      for (int fc = 0; fc < 16; ++fc) {
        int col = fc * 16 + lr;
        short8 b = *reinterpret_cast<const short8*>(
            cB + ((col * 128 + ks * 64 + kg * 16) ^ ((col & 7) << 4)));
        acc[fc] = __builtin_amdgcn_mfma_f32_16x16x32_bf16(a, b, acc[fc], 0, 0, 0);
      }
    }
    __syncthreads();
  }
  float g16[16], b16[16];
#pragma unroll
  for (int fc = 0; fc < 16; ++fc) {
    g16[fc] = g[fc * 16 + lr];
    b16[fc] = bb[fc * 16 + lr];
  }
#pragma unroll
  for (int r = 0; r < 4; ++r) {
    int rowl = kg * 4 + r;
    int grow = row0 + w * 16 + rowl;
    int growc = min(grow, N - 1);
    float xv[16];
    float s = 0.f, ss = 0.f;
#pragma unroll
    for (int fc = 0; fc < 16; ++fc) {
      float v = acc[fc][r] + X[(size_t)growc * 256 + fc * 16 + lr];
      xv[fc] = v;
      s += v;
      ss += v * v;
    }
    s += __shfl_xor(s, 1);  ss += __shfl_xor(ss, 1);
    s += __shfl_xor(s, 2);  ss += __shfl_xor(ss, 2);
    s += __shfl_xor(s, 4);  ss += __shfl_xor(ss, 4);
    s += __shfl_xor(s, 8);  ss += __shfl_xor(ss, 8);
    float mu = s * (1.f / 256.f);
    float var = ss * (1.f / 256.f) - mu * mu;
    float rs = rsqrtf(var + 1e-5f);
    if (grow < N) {
#pragma unroll
      for (int fc = 0; fc < 16; ++fc)
        out[(size_t)grow * 256 + fc * 16 + lr] = (xv[fc] - mu) * rs * g16[fc] + b16[fc];
    }
  }
}

extern "C" void kernel_launch(void* const* d_in, const int* in_sizes, int n_in,
                              void* d_out, int out_size, void* d_ws, size_t ws_size,
                              hipStream_t stream) {
  const float* X  = (const float*)d_in[0];
  const int* eidx = (const int*)d_in[1];
  const float* ew = (const float*)d_in[2];
  const float* Wq = (const float*)d_in[3];
  const float* Wk = (const float*)d_in[4];
  const float* Wv = (const float*)d_in[5];
  const float* We = (const float*)d_in[6];
  const float* Wo = (const float*)d_in[7];
  const float* g  = (const float*)d_in[8];
  const float* b  = (const float*)d_in[9];
  int N = in_sizes[0] / 256;
  int E = in_sizes[1] / 2;
  const int* src = eidx;
  const int* tgt = eidx + E;
  float* out = (float*)d_out;

  char* w = (char*)d_ws;
  ushort* Xb   = (ushort*)w;        w += (size_t)N * 256 * 2;
  ushort* Wt   = (ushort*)w;        w += (size_t)1024 * 256 * 2;
  ushort* Qb   = (ushort*)w;        w += (size_t)N * 256 * 2;
  unsigned char* Kb8 = (unsigned char*)w;  w += (size_t)N * 256;
  unsigned char* Vb8 = (unsigned char*)w;  w += (size_t)N * 256;
  ushort* AGGb = (ushort*)w;        w += (size_t)N * 256 * 2;
  int* counts  = (int*)w;           w += (size_t)N * 4;
  int* offs    = (int*)w;           w += (size_t)(N + 1) * 4;
  int* cursor  = (int*)w;           w += (size_t)N * 4;
  int2* ews    = (int2*)w;          w += (size_t)E * 8;
  const ushort* Wot = Wt + (size_t)768 * 256;

  int nX = N * 256;
  int nxb = (nX / 8 + 255) / 256;
  int nzero = (N + 255) / 256;
  pre_kernel<<<nxb + 256 + nzero, 256, 0, stream>>>(X, Xb, nX, Wq, Wk, Wv, Wo, Wt, counts, N, nxb);

  int ngemm = ((N + 127) / 128) * 6;
  int nhist = (E + 255) / 256;
  qkv_gemm<<<ngemm + nhist, 256, 0, stream>>>(Xb, Wt, Qb, Kb8, Vb8, src, counts, N, E, ngemm);

  scan_kernel<<<1, 1024, 0, stream>>>(counts, offs, cursor, N);
  scatter_kernel<<<(E + 255) / 256, 256, 0, stream>>>(src, tgt, ew, cursor, ews, E);
  attn_kernel<<<(N + 3) / 4, 256, 0, stream>>>(Qb, Kb8, Vb8, offs, ews, We, AGGb, N);
  out_ln<<<(N + 63) / 64, 256, 0, stream>>>(AGGb, Wot, X, g, b, out, N);
}